// Round 3
// baseline (390.881 us; speedup 1.0000x reference)
//
#include <hip/hip_runtime.h>
#include <math.h>

#define BB 32
#define LL 50
#define CC 80
#define AA 3
#define IMGF 480.0f
#define ROWS_TOTAL 14175
#define BOX_OFF 1L
#define SCORE_OFF (1L + (long)BB * ROWS_TOTAL * 4)   // 1814401 floats

// cells per image per level
#define CB0 10800
#define CB1 2700
#define CB2 675
#define NCELLS (BB * (CB0 + CB1 + CB2))   // 453600

// 64 cells per block (256 threads, 4 threads/cell)
#define CH0 169
#define CH1 43
#define CH2 11
#define BLK0 (BB * CH0)   // 5408
#define BLK1 (BB * CH1)   // 1376
#define BLK2 (BB * CH2)   // 352
#define NBLK (BLK0 + BLK1 + BLK2)   // 7136

// workspace layout (byte offsets, all 16B-aligned)
#define WS_MATCH 0                         // int[453600]
#define WS_CREC  (NCELLS * 4)              // float[32*50*8] compacted GT records
#define WS_NVAL  (WS_CREC + BB * LL * 8 * 4)   // int[32]
#define WS_ADJ   (WS_NVAL + 128)           // float[3*32*50*5] adjusted targets
#define WS_PART  (WS_ADJ + 3 * BB * LL * 5 * 4) // float[NBLK] block partials

// native vector type accepted by __builtin_nontemporal_store
typedef float vf4 __attribute__((ext_vector_type(4)));

// ---------------------------------------------------------------------------
// init: fill match table with -1; compact valid GT boxes per image
// ---------------------------------------------------------------------------
__global__ void init_kernel(const float* __restrict__ gt, char* __restrict__ ws)
{
    int idx = blockIdx.x * blockDim.x + threadIdx.x;
    int4* mt = (int4*)(ws + WS_MATCH);
    if (idx < NCELLS / 4) mt[idx] = make_int4(-1, -1, -1, -1);
    if (blockIdx.x == 0 && threadIdx.x < BB) {
        int b = threadIdx.x;
        float* cr = (float*)(ws + WS_CREC) + b * LL * 8;
        int n = 0;
        for (int t = 0; t < LL; ++t) {
            const float* g = gt + (b * LL + t) * 5;
            float x = g[0], y = g[1], w = g[2], h = g[3];
            if (w > 0.0f) {
                float* r = cr + n * 8;
                r[0] = x - 0.5f * w; r[1] = y - 0.5f * h;
                r[2] = x + 0.5f * w; r[3] = y + 0.5f * h;
                r[4] = 0.6f * (w * h); r[5] = 0.f; r[6] = 0.f; r[7] = 0.f;
                n++;
            }
        }
        ((int*)(ws + WS_NVAL))[b] = n;
    }
}

// ---------------------------------------------------------------------------
// prep: per (level,b,t) valid GT: adjusted targets + atomicMax scatter into
// the match table (max t == last-write-wins of the reference scatter).
// ---------------------------------------------------------------------------
__global__ void prep_kernel(const float* __restrict__ gt,
                            const float* __restrict__ anchors,
                            char* __restrict__ ws)
{
    int idx = blockIdx.x * blockDim.x + threadIdx.x;
    if (idx >= 3 * BB * LL) return;
    int t   = idx % LL;
    int b   = (idx / LL) % BB;
    int lvl = idx / (LL * BB);
    int W       = (lvl == 0) ? 60 : (lvl == 1) ? 30 : 15;
    int cells_b = (lvl == 0) ? CB0 : (lvl == 1) ? CB1 : CB2;
    int cellof  = (lvl == 0) ? 0 : (lvl == 1) ? BB * CB0 : BB * (CB0 + CB1);
    float Wf = (float)W;

    const float* g = gt + (b * LL + t) * 5;
    float x = g[0], y = g[1], wd = g[2], ht = g[3], cls = g[4];
    if (wd <= 0.0f) return;
    float bx = x * Wf, by = y * Wf, bw = wd * Wf, bh = ht * Wf;
    int j = min(max((int)floorf(bx), 0), W - 1);
    int i = min(max((int)floorf(by), 0), W - 1);

    float best = -1.0f; int k = 0; float kaw = 1.0f, kah = 1.0f;
#pragma unroll
    for (int kk = 0; kk < AA; ++kk) {
        float aw = anchors[kk * 2 + 0] * Wf;
        float ah = anchors[kk * 2 + 1] * Wf;
        float inter = fminf(bw, aw) * fminf(bh, ah);
        float iou = inter / (bw * bh + aw * ah - inter + 1e-9f);
        if (iou > best) { best = iou; k = kk; kaw = aw; kah = ah; }
    }
    int cell = (i * W + j) * AA + k;
    atomicMax((int*)(ws + WS_MATCH) + cellof + b * cells_b + cell, t);
    float* ad = (float*)(ws + WS_ADJ) + ((lvl * BB + b) * LL + t) * 5;
    ad[0] = bx - (float)j;
    ad[1] = by - (float)i;
    ad[2] = logf(bw / kaw);
    ad[3] = logf(bh / kah);
    ad[4] = cls;
}

// ---------------------------------------------------------------------------
// main: all three levels. 4 threads/cell, 64 cells/block. Round-0 structure
// (direct global loads, no LDS staging) +:
//   - non-temporal stores for scores/boxes (never re-read; stop evicting
//     preds from L2/L3 -> FETCH_SIZE should drop)
//   - ignore loop unrolled x2 (two GT loads in flight)
//   - adj target fetch issued early, latency hidden under the ignore loop
// ---------------------------------------------------------------------------
__global__ __launch_bounds__(256) void main_kernel(
    const float* __restrict__ preds0,
    const float* __restrict__ preds1,
    const float* __restrict__ preds2,
    const float* __restrict__ anchors,
    const char* __restrict__ wsc,
    float* __restrict__ partials,
    float* __restrict__ out)
{
    const int*   matchtbl = (const int*)(wsc + WS_MATCH);
    const float* crec     = (const float*)(wsc + WS_CREC);
    const int*   nval     = (const int*)(wsc + WS_NVAL);
    const float* adj      = (const float*)(wsc + WS_ADJ);

    int bid = blockIdx.x;
    const float* preds; int W, cells_b, rowoff, cellof, b, chunk, lvl;
    float invW; unsigned Wmagic;
    if (bid < BLK0) {
        lvl = 0; preds = preds0; W = 60; invW = 1.0f / 60.0f; Wmagic = 71582789u;
        cells_b = CB0; rowoff = 0; cellof = 0;
        b = bid / CH0; chunk = bid - b * CH0;
    } else if (bid < BLK0 + BLK1) {
        int inner = bid - BLK0;
        lvl = 1; preds = preds1; W = 30; invW = 1.0f / 30.0f; Wmagic = 143165577u;
        cells_b = CB1; rowoff = CB0; cellof = BB * CB0;
        b = inner / CH1; chunk = inner - b * CH1;
    } else {
        int inner = bid - BLK0 - BLK1;
        lvl = 2; preds = preds2; W = 15; invW = 1.0f / 15.0f; Wmagic = 286331154u;
        cells_b = CB2; rowoff = CB0 + CB1; cellof = BB * (CB0 + CB1);
        b = inner / CH2; chunk = inner - b * CH2;
    }

    int tid = threadIdx.x;
    int g   = tid >> 2;
    int sub = tid & 3;
    int cell = chunk * 64 + g;
    bool cvalid = cell < cells_b;
    int cc = cvalid ? cell : (cells_b - 1);

    // decode (a, w, h) from cc
    int t1 = cc / 3;
    int a  = cc - t1 * 3;
    int h  = (int)__umulhi((unsigned)t1, Wmagic);
    int w  = t1 - h * W;

    // ---- issue all independent loads up front ----
    long pbase = ((long)b * cells_b + cc) * 85;
    const float* p = preds + pbase;
    float f0 = p[0], f1 = p[1], f2 = p[2], f3 = p[3], f4 = p[4];

    const float* pc = p + 5 + 4 * sub;
    float4 q0 = *(const float4*)(pc);
    float4 q1 = *(const float4*)(pc + 16);
    float4 q2 = *(const float4*)(pc + 32);
    float4 q3 = *(const float4*)(pc + 48);
    float4 q4 = *(const float4*)(pc + 64);

    int wt = matchtbl[cellof + b * cells_b + cc];
    int nv = nval[b];

    q0.x = __expf(q0.x); q0.y = __expf(q0.y); q0.z = __expf(q0.z); q0.w = __expf(q0.w);
    q1.x = __expf(q1.x); q1.y = __expf(q1.y); q1.z = __expf(q1.z); q1.w = __expf(q1.w);
    q2.x = __expf(q2.x); q2.y = __expf(q2.y); q2.z = __expf(q2.z); q2.w = __expf(q2.w);
    q3.x = __expf(q3.x); q3.y = __expf(q3.y); q3.z = __expf(q3.z); q3.w = __expf(q3.w);
    q4.x = __expf(q4.x); q4.y = __expf(q4.y); q4.z = __expf(q4.z); q4.w = __expf(q4.w);
    float s = (q0.x + q0.y + q0.z + q0.w) + (q1.x + q1.y + q1.z + q1.w)
            + (q2.x + q2.y + q2.z + q2.w) + (q3.x + q3.y + q3.z + q3.w)
            + (q4.x + q4.y + q4.z + q4.w);
    s += __shfl_xor(s, 1);
    s += __shfl_xor(s, 2);
    float invs = __builtin_amdgcn_rcpf(s);

    // early adj fetch (wt already arrived with the preds wait);
    // its latency hides under the ignore loop below
    float ar0 = 0.f, ar1 = 0.f, ar2 = 0.f, ar3 = 0.f; int label = -1;
    if (wt >= 0) {
        const float* ar = adj + ((lvl * BB + b) * LL + wt) * 5;
        ar0 = ar[0]; ar1 = ar[1]; ar2 = ar[2]; ar3 = ar[3];
        label = (int)ar[4];
    }

    float conf = __builtin_amdgcn_rcpf(1.0f + __expf(-f4));
    float bxs  = __builtin_amdgcn_rcpf(1.0f + __expf(-f0));
    float bys  = __builtin_amdgcn_rcpf(1.0f + __expf(-f1));
    float ancw = anchors[2 * a], anch = anchors[2 * a + 1];
    float pw = __expf(f2) * ancw;
    float ph = __expf(f3) * anch;
    float px = (bxs + (float)w) * invW;
    float py = (bys + (float)h) * invW;
    float pminx = px - 0.5f * pw, pmaxx = px + 0.5f * pw;
    float pminy = py - 0.5f * ph, pmaxy = py + 0.5f * ph;
    float pa06 = 0.6f * (pw * ph) + 0.6e-9f;

    // ignore test: any IoU > 0.6  <=>  1.6*inter > 0.6*(pa+ta+1e-9)
    // unrolled x2: two independent GT loads in flight per iteration
    const float* cb = crec + b * LL * 8;
    float amax = -1.0f;
    int t = sub;
    for (; t + 4 < nv; t += 8) {
        const float* r0 = cb + t * 8;
        const float* r1 = r0 + 32;
        float4 tb0 = *(const float4*)r0; float ta0 = r0[4];
        float4 tb1 = *(const float4*)r1; float ta1 = r1[4];
        float ix0 = fmaxf(fminf(pmaxx, tb0.z) - fmaxf(pminx, tb0.x), 0.0f);
        float iy0 = fmaxf(fminf(pmaxy, tb0.w) - fmaxf(pminy, tb0.y), 0.0f);
        amax = fmaxf(amax, 1.6f * (ix0 * iy0) - (pa06 + ta0));
        float ix1 = fmaxf(fminf(pmaxx, tb1.z) - fmaxf(pminx, tb1.x), 0.0f);
        float iy1 = fmaxf(fminf(pmaxy, tb1.w) - fmaxf(pminy, tb1.y), 0.0f);
        amax = fmaxf(amax, 1.6f * (ix1 * iy1) - (pa06 + ta1));
    }
    if (t < nv) {
        const float* r = cb + t * 8;
        float4 tb = *(const float4*)r; float ta = r[4];
        float ix = fmaxf(fminf(pmaxx, tb.z) - fmaxf(pminx, tb.x), 0.0f);
        float iy = fmaxf(fminf(pmaxy, tb.w) - fmaxf(pminy, tb.y), 0.0f);
        amax = fmaxf(amax, 1.6f * (ix * iy) - (pa06 + ta));
    }
    unsigned long long bal = __ballot(amax > 0.0f);
    bool objdet = ((bal >> (tid & 60)) & 0xFULL) != 0ULL;

    float partial = 0.0f;
    float ci = conf * invs;
    if (cvalid) {
        long rb = (long)b * ROWS_TOTAL + rowoff + cell;
        float* sb = out + SCORE_OFF + rb * CC + 4 * sub;
        vf4 o;
        o.x = q0.x * ci; o.y = q0.y * ci; o.z = q0.z * ci; o.w = q0.w * ci;
        __builtin_nontemporal_store(o, (vf4*)(sb));
        o.x = q1.x * ci; o.y = q1.y * ci; o.z = q1.z * ci; o.w = q1.w * ci;
        __builtin_nontemporal_store(o, (vf4*)(sb + 16));
        o.x = q2.x * ci; o.y = q2.y * ci; o.z = q2.z * ci; o.w = q2.w * ci;
        __builtin_nontemporal_store(o, (vf4*)(sb + 32));
        o.x = q3.x * ci; o.y = q3.y * ci; o.z = q3.z * ci; o.w = q3.w * ci;
        __builtin_nontemporal_store(o, (vf4*)(sb + 48));
        o.x = q4.x * ci; o.y = q4.y * ci; o.z = q4.z * ci; o.w = q4.w * ci;
        __builtin_nontemporal_store(o, (vf4*)(sb + 64));
        {
            float comp = (sub == 0) ? pminx : (sub == 1) ? pminy
                       : (sub == 2) ? pmaxx : pmaxy;
            __builtin_nontemporal_store(comp * IMGF, out + BOX_OFF + rb * 4 + sub);
        }

        if (wt >= 0) {
            int c = 4 * sub;
            float d;
            d = ((c +  0) == label ? 1.0f : 0.0f) - q0.x * invs; partial += d * d;
            d = ((c +  1) == label ? 1.0f : 0.0f) - q0.y * invs; partial += d * d;
            d = ((c +  2) == label ? 1.0f : 0.0f) - q0.z * invs; partial += d * d;
            d = ((c +  3) == label ? 1.0f : 0.0f) - q0.w * invs; partial += d * d;
            d = ((c + 16) == label ? 1.0f : 0.0f) - q1.x * invs; partial += d * d;
            d = ((c + 17) == label ? 1.0f : 0.0f) - q1.y * invs; partial += d * d;
            d = ((c + 18) == label ? 1.0f : 0.0f) - q1.z * invs; partial += d * d;
            d = ((c + 19) == label ? 1.0f : 0.0f) - q1.w * invs; partial += d * d;
            d = ((c + 32) == label ? 1.0f : 0.0f) - q2.x * invs; partial += d * d;
            d = ((c + 33) == label ? 1.0f : 0.0f) - q2.y * invs; partial += d * d;
            d = ((c + 34) == label ? 1.0f : 0.0f) - q2.z * invs; partial += d * d;
            d = ((c + 35) == label ? 1.0f : 0.0f) - q2.w * invs; partial += d * d;
            d = ((c + 48) == label ? 1.0f : 0.0f) - q3.x * invs; partial += d * d;
            d = ((c + 49) == label ? 1.0f : 0.0f) - q3.y * invs; partial += d * d;
            d = ((c + 50) == label ? 1.0f : 0.0f) - q3.z * invs; partial += d * d;
            d = ((c + 51) == label ? 1.0f : 0.0f) - q3.w * invs; partial += d * d;
            d = ((c + 64) == label ? 1.0f : 0.0f) - q4.x * invs; partial += d * d;
            d = ((c + 65) == label ? 1.0f : 0.0f) - q4.y * invs; partial += d * d;
            d = ((c + 66) == label ? 1.0f : 0.0f) - q4.z * invs; partial += d * d;
            d = ((c + 67) == label ? 1.0f : 0.0f) - q4.w * invs; partial += d * d;
            if (sub == 0) {
                float c0 = ar0 - bxs, c1 = ar1 - bys;
                float c2 = ar2 - f2,  c3 = ar3 - f3;
                partial += c0 * c0 + c1 * c1 + c2 * c2 + c3 * c3;   // coord
                float u = 1.0f - conf;
                partial += 5.0f * u * u;                            // obj
            }
        } else if (sub == 0) {
            partial += (objdet ? 0.0f : 1.0f) * conf * conf;        // noobj
        }
    }

    // block reduction -> one partial store
    float vsum = partial;
#pragma unroll
    for (int off = 32; off; off >>= 1) vsum += __shfl_xor(vsum, off);
    __shared__ float red[4];
    int wave = tid >> 6;
    if ((tid & 63) == 0) red[wave] = vsum;
    __syncthreads();
    if (tid == 0) partials[bid] = 0.5f * (red[0] + red[1] + red[2] + red[3]);
}

__global__ void reduce_kernel(const float* __restrict__ partials,
                              float* __restrict__ out)
{
    __shared__ float red[4];
    float s = 0.0f;
    for (int i = threadIdx.x; i < NBLK; i += 256) s += partials[i];
#pragma unroll
    for (int off = 32; off; off >>= 1) s += __shfl_xor(s, off);
    int wave = threadIdx.x >> 6;
    if ((threadIdx.x & 63) == 0) red[wave] = s;
    __syncthreads();
    if (threadIdx.x == 0) out[0] = red[0] + red[1] + red[2] + red[3];
}

extern "C" void kernel_launch(void* const* d_in, const int* in_sizes, int n_in,
                              void* d_out, int out_size, void* d_ws, size_t ws_size,
                              hipStream_t stream)
{
    const float* preds0  = (const float*)d_in[0];
    const float* preds1  = (const float*)d_in[1];
    const float* preds2  = (const float*)d_in[2];
    const float* gt      = (const float*)d_in[3];
    const float* anchors = (const float*)d_in[4];
    float* out = (float*)d_out;
    char* ws = (char*)d_ws;

    init_kernel<<<(NCELLS / 4 + 255) / 256, 256, 0, stream>>>(gt, ws);
    prep_kernel<<<(3 * BB * LL + 255) / 256, 256, 0, stream>>>(gt, anchors, ws);
    main_kernel<<<NBLK, 256, 0, stream>>>(preds0, preds1, preds2, anchors,
                                          (const char*)ws,
                                          (float*)(ws + WS_PART), out);
    reduce_kernel<<<1, 256, 0, stream>>>((const float*)(ws + WS_PART), out);
}

// Round 4
// 329.409 us; speedup vs baseline: 1.1866x; 1.1866x over previous
//
#include <hip/hip_runtime.h>
#include <math.h>

#define BB 32
#define LL 50
#define CC 80
#define AA 3
#define IMGF 480.0f
#define ROWS_TOTAL 14175
#define BOX_OFF 1L
#define SCORE_OFF (1L + (long)BB * ROWS_TOTAL * 4)   // 1814401 floats

// cells per image per level
#define CB0 10800
#define CB1 2700
#define CB2 675
#define NCELLS (BB * (CB0 + CB1 + CB2))   // 453600

// 64 cells per block (256 threads, 4 threads/cell)
#define CH0 169
#define CH1 43
#define CH2 11
#define BLK0 (BB * CH0)   // 5408
#define BLK1 (BB * CH1)   // 1376
#define BLK2 (BB * CH2)   // 352
#define NBLK (BLK0 + BLK1 + BLK2)   // 7136

// workspace layout (byte offsets, all 16B-aligned)
#define WS_MATCH 0                         // int[453600]
#define WS_CREC  (NCELLS * 4)              // float[32*50*8] compacted GT records
#define WS_NVAL  (WS_CREC + BB * LL * 8 * 4)   // int[32]
#define WS_ADJ   (WS_NVAL + 128)           // float[3*32*50*5] adjusted targets
#define WS_PART  (WS_ADJ + 3 * BB * LL * 5 * 4) // float[NBLK] block partials

// ---------------------------------------------------------------------------
// init: fill match table with -1; compact valid GT boxes per image
// ---------------------------------------------------------------------------
__global__ void init_kernel(const float* __restrict__ gt, char* __restrict__ ws)
{
    int idx = blockIdx.x * blockDim.x + threadIdx.x;
    int4* mt = (int4*)(ws + WS_MATCH);
    if (idx < NCELLS / 4) mt[idx] = make_int4(-1, -1, -1, -1);
    if (blockIdx.x == 0 && threadIdx.x < BB) {
        int b = threadIdx.x;
        float* cr = (float*)(ws + WS_CREC) + b * LL * 8;
        int n = 0;
        for (int t = 0; t < LL; ++t) {
            const float* g = gt + (b * LL + t) * 5;
            float x = g[0], y = g[1], w = g[2], h = g[3];
            if (w > 0.0f) {
                float* r = cr + n * 8;
                r[0] = x - 0.5f * w; r[1] = y - 0.5f * h;
                r[2] = x + 0.5f * w; r[3] = y + 0.5f * h;
                r[4] = 0.6f * (w * h); r[5] = 0.f; r[6] = 0.f; r[7] = 0.f;
                n++;
            }
        }
        ((int*)(ws + WS_NVAL))[b] = n;
    }
}

// ---------------------------------------------------------------------------
// prep: per (level,b,t) valid GT: adjusted targets + atomicMax scatter into
// the match table (max t == last-write-wins of the reference scatter).
// ---------------------------------------------------------------------------
__global__ void prep_kernel(const float* __restrict__ gt,
                            const float* __restrict__ anchors,
                            char* __restrict__ ws)
{
    int idx = blockIdx.x * blockDim.x + threadIdx.x;
    if (idx >= 3 * BB * LL) return;
    int t   = idx % LL;
    int b   = (idx / LL) % BB;
    int lvl = idx / (LL * BB);
    int W       = (lvl == 0) ? 60 : (lvl == 1) ? 30 : 15;
    int cells_b = (lvl == 0) ? CB0 : (lvl == 1) ? CB1 : CB2;
    int cellof  = (lvl == 0) ? 0 : (lvl == 1) ? BB * CB0 : BB * (CB0 + CB1);
    float Wf = (float)W;

    const float* g = gt + (b * LL + t) * 5;
    float x = g[0], y = g[1], wd = g[2], ht = g[3], cls = g[4];
    if (wd <= 0.0f) return;
    float bx = x * Wf, by = y * Wf, bw = wd * Wf, bh = ht * Wf;
    int j = min(max((int)floorf(bx), 0), W - 1);
    int i = min(max((int)floorf(by), 0), W - 1);

    float best = -1.0f; int k = 0; float kaw = 1.0f, kah = 1.0f;
#pragma unroll
    for (int kk = 0; kk < AA; ++kk) {
        float aw = anchors[kk * 2 + 0] * Wf;
        float ah = anchors[kk * 2 + 1] * Wf;
        float inter = fminf(bw, aw) * fminf(bh, ah);
        float iou = inter / (bw * bh + aw * ah - inter + 1e-9f);
        if (iou > best) { best = iou; k = kk; kaw = aw; kah = ah; }
    }
    int cell = (i * W + j) * AA + k;
    atomicMax((int*)(ws + WS_MATCH) + cellof + b * cells_b + cell, t);
    float* ad = (float*)(ws + WS_ADJ) + ((lvl * BB + b) * LL + t) * 5;
    ad[0] = bx - (float)j;
    ad[1] = by - (float)i;
    ad[2] = logf(bw / kaw);
    ad[3] = logf(bh / kah);
    ad[4] = cls;
}

// ---------------------------------------------------------------------------
// main: all three levels. 4 threads/cell, 64 cells/block.
// Input-side LDS staging ONLY (coalesced float4 global->LDS, minimal line
// transactions), GT records in LDS, ONE barrier. Output path = round-0
// direct float4 global stores (proven fastest; alignment doesn't matter
// for WRITE_SIZE because L2 write-combines).
// ---------------------------------------------------------------------------
__global__ __launch_bounds__(256) void main_kernel(
    const float* __restrict__ preds0,
    const float* __restrict__ preds1,
    const float* __restrict__ preds2,
    const float* __restrict__ anchors,
    const char* __restrict__ wsc,
    float* __restrict__ partials,
    float* __restrict__ out)
{
    __shared__ __align__(16) float lds[5448];      // preds slab (<= 3 + 64*85)
    __shared__ __align__(16) float gtrec[LL * 8];  // 400 floats
    __shared__ float red[4];

    const int*   matchtbl = (const int*)(wsc + WS_MATCH);
    const float* crec     = (const float*)(wsc + WS_CREC);
    const int*   nval     = (const int*)(wsc + WS_NVAL);
    const float* adj      = (const float*)(wsc + WS_ADJ);

    int bid = blockIdx.x;
    const float* preds; int W, cells_b, rowoff, cellof, b, chunk, lvl;
    float invW; unsigned Wmagic;
    if (bid < BLK0) {
        lvl = 0; preds = preds0; W = 60; invW = 1.0f / 60.0f; Wmagic = 71582789u;
        cells_b = CB0; rowoff = 0; cellof = 0;
        b = bid / CH0; chunk = bid - b * CH0;
    } else if (bid < BLK0 + BLK1) {
        int inner = bid - BLK0;
        lvl = 1; preds = preds1; W = 30; invW = 1.0f / 30.0f; Wmagic = 143165577u;
        cells_b = CB1; rowoff = CB0; cellof = BB * CB0;
        b = inner / CH1; chunk = inner - b * CH1;
    } else {
        int inner = bid - BLK0 - BLK1;
        lvl = 2; preds = preds2; W = 15; invW = 1.0f / 15.0f; Wmagic = 286331154u;
        cells_b = CB2; rowoff = CB0 + CB1; cellof = BB * (CB0 + CB1);
        b = inner / CH2; chunk = inner - b * CH2;
    }

    int tid = threadIdx.x;
    int g   = tid >> 2;
    int sub = tid & 3;
    int ncell = cells_b - chunk * 64; if (ncell > 64) ncell = 64;
    bool cvalid = g < ncell;
    int lc = cvalid ? g : (ncell - 1);        // clamped local cell
    int cellg = chunk * 64 + lc;              // clamped global cell (in image)

    // ---- stage preds slab -> LDS (aligned coalesced float4 stream) ----
    long S = ((long)b * cells_b + chunk * 64) * 85;   // first float of slab
    int off0 = (int)(S & 3);
    long Sa = S - off0;                                // 16B-aligned float index
    int nf = off0 + ncell * 85;                        // floats to stage
    int n4 = nf >> 2;
    const float4* s4 = (const float4*)(preds + Sa);
    for (int i = tid; i < n4; i += 256) ((float4*)lds)[i] = s4[i];
    if (tid < (nf & 3)) lds[(n4 << 2) + tid] = preds[Sa + (n4 << 2) + tid];

    // ---- stage GT records -> LDS ----
    if (tid < 100) ((float4*)gtrec)[tid] = ((const float4*)(crec + b * LL * 8))[tid];

    // global loads that can fly across the barrier
    int wt = matchtbl[cellof + b * cells_b + cellg];
    int nv = nval[b];
    __syncthreads();

    // ---- fragments from LDS ----
    int base = off0 + lc * 85;
    float f0 = lds[base + 0], f1 = lds[base + 1], f2 = lds[base + 2];
    float f3 = lds[base + 3], f4 = lds[base + 4];
    float q[20];
#pragma unroll
    for (int k = 0; k < 5; ++k)
#pragma unroll
        for (int j = 0; j < 4; ++j)
            q[4 * k + j] = lds[base + 5 + 4 * sub + 16 * k + j];

    // ---- softmax numerators + quad sum ----
#pragma unroll
    for (int k = 0; k < 20; ++k) q[k] = __expf(q[k]);
    float s = 0.0f;
#pragma unroll
    for (int k = 0; k < 20; ++k) s += q[k];
    s += __shfl_xor(s, 1);
    s += __shfl_xor(s, 2);
    float invs = __builtin_amdgcn_rcpf(s);

    // early adj fetch; latency hides under the ignore loop below
    float ar0 = 0.f, ar1 = 0.f, ar2 = 0.f, ar3 = 0.f; int label = -1;
    if (wt >= 0) {
        const float* ar = adj + ((lvl * BB + b) * LL + wt) * 5;
        ar0 = ar[0]; ar1 = ar[1]; ar2 = ar[2]; ar3 = ar[3];
        label = (int)ar[4];
    }

    float conf = __builtin_amdgcn_rcpf(1.0f + __expf(-f4));
    float bxs  = __builtin_amdgcn_rcpf(1.0f + __expf(-f0));
    float bys  = __builtin_amdgcn_rcpf(1.0f + __expf(-f1));

    // geometry
    int t1 = cellg / 3;
    int a  = cellg - t1 * 3;
    int hh = (int)__umulhi((unsigned)t1, Wmagic);
    int ww = t1 - hh * W;
    float ancw = anchors[2 * a], anch = anchors[2 * a + 1];
    float pw = __expf(f2) * ancw;
    float ph = __expf(f3) * anch;
    float px = (bxs + (float)ww) * invW;
    float py = (bys + (float)hh) * invW;
    float pminx = px - 0.5f * pw, pmaxx = px + 0.5f * pw;
    float pminy = py - 0.5f * ph, pmaxy = py + 0.5f * ph;
    float pa06 = 0.6f * (pw * ph) + 0.6e-9f;

    // ---- ignore test from LDS GT records ----
    // any IoU > 0.6  <=>  1.6*inter > 0.6*(pa+ta+1e-9)
    float amax = -1.0f;
    for (int t = sub; t < nv; t += 4) {
        const float* r = gtrec + t * 8;
        float ix = fmaxf(fminf(pmaxx, r[2]) - fmaxf(pminx, r[0]), 0.0f);
        float iy = fmaxf(fminf(pmaxy, r[3]) - fmaxf(pminy, r[1]), 0.0f);
        amax = fmaxf(amax, 1.6f * (ix * iy) - (pa06 + r[4]));
    }
    unsigned long long bal = __ballot(amax > 0.0f);
    bool objdet = ((bal >> (tid & 60)) & 0xFULL) != 0ULL;

    // ---- outputs + losses (round-0 direct-store path) ----
    float partial = 0.0f;
    float ci = conf * invs;
    if (cvalid) {
        long rb = (long)b * ROWS_TOTAL + rowoff + cellg;
        float* sb = out + SCORE_OFF + rb * CC + 4 * sub;
#pragma unroll
        for (int k = 0; k < 5; ++k) {
            float4 o = make_float4(q[4 * k + 0] * ci, q[4 * k + 1] * ci,
                                   q[4 * k + 2] * ci, q[4 * k + 3] * ci);
            *(float4*)(sb + 16 * k) = o;
        }
        {
            float comp = (sub == 0) ? pminx : (sub == 1) ? pminy
                       : (sub == 2) ? pmaxx : pmaxy;
            out[BOX_OFF + rb * 4 + sub] = comp * IMGF;
        }

        if (wt >= 0) {
            int c = 4 * sub;
#pragma unroll
            for (int k = 0; k < 5; ++k)
#pragma unroll
                for (int j = 0; j < 4; ++j) {
                    float d = ((c + 16 * k + j) == label ? 1.0f : 0.0f)
                            - q[4 * k + j] * invs;
                    partial += d * d;
                }
            if (sub == 0) {
                float c0 = ar0 - bxs, c1 = ar1 - bys;
                float c2 = ar2 - f2,  c3 = ar3 - f3;
                partial += c0 * c0 + c1 * c1 + c2 * c2 + c3 * c3;   // coord
                float u = 1.0f - conf;
                partial += 5.0f * u * u;                            // obj
            }
        } else if (sub == 0) {
            partial += (objdet ? 0.0f : 1.0f) * conf * conf;        // noobj
        }
    }

    // block reduction -> one partial store
    float vsum = partial;
#pragma unroll
    for (int off = 32; off; off >>= 1) vsum += __shfl_xor(vsum, off);
    int wave = tid >> 6;
    if ((tid & 63) == 0) red[wave] = vsum;
    __syncthreads();
    if (tid == 0) partials[bid] = 0.5f * (red[0] + red[1] + red[2] + red[3]);
}

__global__ void reduce_kernel(const float* __restrict__ partials,
                              float* __restrict__ out)
{
    __shared__ float red[4];
    float s = 0.0f;
    for (int i = threadIdx.x; i < NBLK; i += 256) s += partials[i];
#pragma unroll
    for (int off = 32; off; off >>= 1) s += __shfl_xor(s, off);
    int wave = threadIdx.x >> 6;
    if ((threadIdx.x & 63) == 0) red[wave] = s;
    __syncthreads();
    if (threadIdx.x == 0) out[0] = red[0] + red[1] + red[2] + red[3];
}

extern "C" void kernel_launch(void* const* d_in, const int* in_sizes, int n_in,
                              void* d_out, int out_size, void* d_ws, size_t ws_size,
                              hipStream_t stream)
{
    const float* preds0  = (const float*)d_in[0];
    const float* preds1  = (const float*)d_in[1];
    const float* preds2  = (const float*)d_in[2];
    const float* gt      = (const float*)d_in[3];
    const float* anchors = (const float*)d_in[4];
    float* out = (float*)d_out;
    char* ws = (char*)d_ws;

    init_kernel<<<(NCELLS / 4 + 255) / 256, 256, 0, stream>>>(gt, ws);
    prep_kernel<<<(3 * BB * LL + 255) / 256, 256, 0, stream>>>(gt, anchors, ws);
    main_kernel<<<NBLK, 256, 0, stream>>>(preds0, preds1, preds2, anchors,
                                          (const char*)ws,
                                          (float*)(ws + WS_PART), out);
    reduce_kernel<<<1, 256, 0, stream>>>((const float*)(ws + WS_PART), out);
}

// Round 5
// 285.816 us; speedup vs baseline: 1.3676x; 1.1525x over previous
//
#include <hip/hip_runtime.h>
#include <math.h>

#define BB 32
#define LL 50
#define CC 80
#define AA 3
#define IMGF 480.0f
#define ROWS_TOTAL 14175
#define BOX_OFF 1L
#define SCORE_OFF (1L + (long)BB * ROWS_TOTAL * 4)   // 1814401 floats

// cells per image per level
#define CB0 10800
#define CB1 2700
#define CB2 675

// 64 cells per block (256 threads, 4 threads/cell)
#define CH0 169
#define CH1 43
#define CH2 11
#define BLK0 (BB * CH0)   // 5408
#define BLK1 (BB * CH1)   // 1376
#define BLK2 (BB * CH2)   // 352
#define NBLK (BLK0 + BLK1 + BLK2)   // 7136

// workspace layout (byte offsets, all 16B-aligned)
// crec record: [x, y, w, h, cls, kpack, 0.6*w*h, pad]
#define WS_CREC  0                          // float[32*50*8]
#define WS_NVAL  (BB * LL * 8 * 4)          // int[32]
#define WS_PART  (WS_NVAL + 128)            // float[NBLK]

// ---------------------------------------------------------------------------
// setup: wave-parallel per-image compaction of valid GT boxes + per-level
// best-anchor (packed 2 bits/level, each level's scale -> replicates the
// reference's per-level argmax incl. the 1e-9 term). One wave per image.
// ---------------------------------------------------------------------------
__global__ __launch_bounds__(64) void setup_kernel(const float* __restrict__ gt,
                                                   const float* __restrict__ anchors,
                                                   char* __restrict__ ws)
{
    int b    = blockIdx.x;    // 0..31
    int lane = threadIdx.x;   // 0..63
    float x = 0.f, y = 0.f, w = 0.f, h = 0.f, cls = 0.f;
    bool valid = false;
    if (lane < LL) {
        const float* g = gt + (b * LL + lane) * 5;
        x = g[0]; y = g[1]; w = g[2]; h = g[3]; cls = g[4];
        valid = (w > 0.0f);
    }
    unsigned long long m = __ballot(valid);
    int pos = (int)__popcll(m & ((1ull << lane) - 1ull));
    if (lane == 0) ((int*)(ws + WS_NVAL))[b] = (int)__popcll(m);
    if (valid) {
        int kpack = 0;
#pragma unroll
        for (int lvl = 0; lvl < 3; ++lvl) {
            float Wf = (lvl == 0) ? 60.f : (lvl == 1) ? 30.f : 15.f;
            float bw = w * Wf, bh = h * Wf;
            float best = -1.0f; int kb = 0;
#pragma unroll
            for (int kk = 0; kk < AA; ++kk) {
                float aw = anchors[kk * 2 + 0] * Wf;
                float ah = anchors[kk * 2 + 1] * Wf;
                float inter = fminf(bw, aw) * fminf(bh, ah);
                float iou = inter / (bw * bh + aw * ah - inter + 1e-9f);
                if (iou > best) { best = iou; kb = kk; }   // strict >: first-wins
            }
            kpack |= kb << (2 * lvl);
        }
        float* r = (float*)(ws + WS_CREC) + (b * LL + pos) * 8;
        r[0] = x; r[1] = y; r[2] = w; r[3] = h;
        r[4] = cls; r[5] = (float)kpack; r[6] = 0.6f * (w * h); r[7] = 0.f;
    }
}

// ---------------------------------------------------------------------------
// main: all three levels. 4 threads/cell, 64 cells/block. Round-0 memory
// path (direct global loads/stores — proven fastest in R1/R3/R4 ablations).
// Matching fused into the ignore loop (no match table, no prep kernel):
// wt = max t among valid GTs whose target cell == this cell (== reference's
// last-write-wins scatter); adj recomputed on the fly for matched cells.
// ---------------------------------------------------------------------------
__global__ __launch_bounds__(256) void main_kernel(
    const float* __restrict__ preds0,
    const float* __restrict__ preds1,
    const float* __restrict__ preds2,
    const float* __restrict__ anchors,
    const char* __restrict__ wsc,
    float* __restrict__ partials,
    float* __restrict__ out)
{
    const float* crec = (const float*)(wsc + WS_CREC);
    const int*   nval = (const int*)(wsc + WS_NVAL);

    int bid = blockIdx.x;
    const float* preds; int W, cells_b, rowoff, b, chunk, lvl;
    float invW; unsigned Wmagic;
    if (bid < BLK0) {
        lvl = 0; preds = preds0; W = 60; invW = 1.0f / 60.0f; Wmagic = 71582789u;
        cells_b = CB0; rowoff = 0;
        b = bid / CH0; chunk = bid - b * CH0;
    } else if (bid < BLK0 + BLK1) {
        int inner = bid - BLK0;
        lvl = 1; preds = preds1; W = 30; invW = 1.0f / 30.0f; Wmagic = 143165577u;
        cells_b = CB1; rowoff = CB0;
        b = inner / CH1; chunk = inner - b * CH1;
    } else {
        int inner = bid - BLK0 - BLK1;
        lvl = 2; preds = preds2; W = 15; invW = 1.0f / 15.0f; Wmagic = 286331154u;
        cells_b = CB2; rowoff = CB0 + CB1;
        b = inner / CH2; chunk = inner - b * CH2;
    }
    float Wf = (float)W;

    int tid = threadIdx.x;
    int g   = tid >> 2;
    int sub = tid & 3;
    int cell = chunk * 64 + g;
    bool cvalid = cell < cells_b;
    int cc = cvalid ? cell : (cells_b - 1);

    // decode (a, w, h) from cc
    int t1 = cc / 3;
    int a  = cc - t1 * 3;
    int h  = (int)__umulhi((unsigned)t1, Wmagic);
    int w  = t1 - h * W;

    // ---- issue all independent loads up front ----
    long pbase = ((long)b * cells_b + cc) * 85;
    const float* p = preds + pbase;
    float f0 = p[0], f1 = p[1], f2 = p[2], f3 = p[3], f4 = p[4];

    const float* pc = p + 5 + 4 * sub;
    float4 q0 = *(const float4*)(pc);
    float4 q1 = *(const float4*)(pc + 16);
    float4 q2 = *(const float4*)(pc + 32);
    float4 q3 = *(const float4*)(pc + 48);
    float4 q4 = *(const float4*)(pc + 64);

    int nv = nval[b];

    q0.x = __expf(q0.x); q0.y = __expf(q0.y); q0.z = __expf(q0.z); q0.w = __expf(q0.w);
    q1.x = __expf(q1.x); q1.y = __expf(q1.y); q1.z = __expf(q1.z); q1.w = __expf(q1.w);
    q2.x = __expf(q2.x); q2.y = __expf(q2.y); q2.z = __expf(q2.z); q2.w = __expf(q2.w);
    q3.x = __expf(q3.x); q3.y = __expf(q3.y); q3.z = __expf(q3.z); q3.w = __expf(q3.w);
    q4.x = __expf(q4.x); q4.y = __expf(q4.y); q4.z = __expf(q4.z); q4.w = __expf(q4.w);
    float s = (q0.x + q0.y + q0.z + q0.w) + (q1.x + q1.y + q1.z + q1.w)
            + (q2.x + q2.y + q2.z + q2.w) + (q3.x + q3.y + q3.z + q3.w)
            + (q4.x + q4.y + q4.z + q4.w);
    s += __shfl_xor(s, 1);
    s += __shfl_xor(s, 2);
    float invs = __builtin_amdgcn_rcpf(s);

    float conf = __builtin_amdgcn_rcpf(1.0f + __expf(-f4));
    float bxs  = __builtin_amdgcn_rcpf(1.0f + __expf(-f0));
    float bys  = __builtin_amdgcn_rcpf(1.0f + __expf(-f1));
    float ancw = anchors[2 * a], anch = anchors[2 * a + 1];
    float pw = __expf(f2) * ancw;
    float ph = __expf(f3) * anch;
    float px = (bxs + (float)w) * invW;
    float py = (bys + (float)h) * invW;
    float pminx = px - 0.5f * pw, pmaxx = px + 0.5f * pw;
    float pminy = py - 0.5f * ph, pmaxy = py + 0.5f * ph;
    float pa06 = 0.6f * (pw * ph) + 0.6e-9f;

    // ---- fused ignore test + matching scan over GT records ----
    // ignore: any IoU > 0.6  <=>  1.6*inter > 0.6*(pa+ta+1e-9)
    // match:  cell_of(GT) == my cell -> track max t (last-write-wins)
    const float* cb = crec + b * LL * 8;
    float amax = -1.0f;
    int wtloc = -1;
    for (int t = sub; t < nv; t += 4) {
        const float* r = cb + t * 8;
        float4 rA = *(const float4*)r;        // x,y,w,h
        float4 rB = *(const float4*)(r + 4);  // cls,kpack,area06,pad
        float tminx = rA.x - 0.5f * rA.z, tmaxx = rA.x + 0.5f * rA.z;
        float tminy = rA.y - 0.5f * rA.w, tmaxy = rA.y + 0.5f * rA.w;
        float ix = fmaxf(fminf(pmaxx, tmaxx) - fmaxf(pminx, tminx), 0.0f);
        float iy = fmaxf(fminf(pmaxy, tmaxy) - fmaxf(pminy, tminy), 0.0f);
        amax = fmaxf(amax, 1.6f * (ix * iy) - (pa06 + rB.z));
        // matching
        float bxg = rA.x * Wf, byg = rA.y * Wf;
        int jg = min(max((int)floorf(bxg), 0), W - 1);
        int ig = min(max((int)floorf(byg), 0), W - 1);
        int kg = (((int)rB.y) >> (2 * lvl)) & 3;
        int cellt = (ig * W + jg) * 3 + kg;
        if (cellt == cc) wtloc = (t > wtloc) ? t : wtloc;
    }
    unsigned long long bal = __ballot(amax > 0.0f);
    bool objdet = ((bal >> (tid & 60)) & 0xFULL) != 0ULL;

    // combine wt across the quad
    {
        int o1 = __shfl_xor(wtloc, 1); wtloc = (o1 > wtloc) ? o1 : wtloc;
        int o2 = __shfl_xor(wtloc, 2); wtloc = (o2 > wtloc) ? o2 : wtloc;
    }
    int wt = wtloc;

    // adj targets recomputed on the fly for the matched GT (rare path)
    float ar0 = 0.f, ar1 = 0.f, ar2 = 0.f, ar3 = 0.f; int label = -1;
    if (wt >= 0) {
        const float* r = cb + wt * 8;
        label = (int)r[4];
        if (sub == 0) {
            float bxg = r[0] * Wf, byg = r[1] * Wf;
            float bwg = r[2] * Wf, bhg = r[3] * Wf;
            int jg = min(max((int)floorf(bxg), 0), W - 1);
            int ig = min(max((int)floorf(byg), 0), W - 1);
            int kg = (((int)r[5]) >> (2 * lvl)) & 3;
            float kaw = anchors[2 * kg + 0] * Wf;
            float kah = anchors[2 * kg + 1] * Wf;
            ar0 = bxg - (float)jg;
            ar1 = byg - (float)ig;
            ar2 = logf(bwg / kaw);
            ar3 = logf(bhg / kah);
        }
    }

    float partial = 0.0f;
    float ci = conf * invs;
    if (cvalid) {
        long rb = (long)b * ROWS_TOTAL + rowoff + cell;
        float* sb = out + SCORE_OFF + rb * CC + 4 * sub;
        float4 o;
        o.x = q0.x * ci; o.y = q0.y * ci; o.z = q0.z * ci; o.w = q0.w * ci; *(float4*)(sb)      = o;
        o.x = q1.x * ci; o.y = q1.y * ci; o.z = q1.z * ci; o.w = q1.w * ci; *(float4*)(sb + 16) = o;
        o.x = q2.x * ci; o.y = q2.y * ci; o.z = q2.z * ci; o.w = q2.w * ci; *(float4*)(sb + 32) = o;
        o.x = q3.x * ci; o.y = q3.y * ci; o.z = q3.z * ci; o.w = q3.w * ci; *(float4*)(sb + 48) = o;
        o.x = q4.x * ci; o.y = q4.y * ci; o.z = q4.z * ci; o.w = q4.w * ci; *(float4*)(sb + 64) = o;
        {
            float comp = (sub == 0) ? pminx : (sub == 1) ? pminy
                       : (sub == 2) ? pmaxx : pmaxy;
            out[BOX_OFF + rb * 4 + sub] = comp * IMGF;
        }

        if (wt >= 0) {
            int c = 4 * sub;
            float d;
            d = ((c +  0) == label ? 1.0f : 0.0f) - q0.x * invs; partial += d * d;
            d = ((c +  1) == label ? 1.0f : 0.0f) - q0.y * invs; partial += d * d;
            d = ((c +  2) == label ? 1.0f : 0.0f) - q0.z * invs; partial += d * d;
            d = ((c +  3) == label ? 1.0f : 0.0f) - q0.w * invs; partial += d * d;
            d = ((c + 16) == label ? 1.0f : 0.0f) - q1.x * invs; partial += d * d;
            d = ((c + 17) == label ? 1.0f : 0.0f) - q1.y * invs; partial += d * d;
            d = ((c + 18) == label ? 1.0f : 0.0f) - q1.z * invs; partial += d * d;
            d = ((c + 19) == label ? 1.0f : 0.0f) - q1.w * invs; partial += d * d;
            d = ((c + 32) == label ? 1.0f : 0.0f) - q2.x * invs; partial += d * d;
            d = ((c + 33) == label ? 1.0f : 0.0f) - q2.y * invs; partial += d * d;
            d = ((c + 34) == label ? 1.0f : 0.0f) - q2.z * invs; partial += d * d;
            d = ((c + 35) == label ? 1.0f : 0.0f) - q2.w * invs; partial += d * d;
            d = ((c + 48) == label ? 1.0f : 0.0f) - q3.x * invs; partial += d * d;
            d = ((c + 49) == label ? 1.0f : 0.0f) - q3.y * invs; partial += d * d;
            d = ((c + 50) == label ? 1.0f : 0.0f) - q3.z * invs; partial += d * d;
            d = ((c + 51) == label ? 1.0f : 0.0f) - q3.w * invs; partial += d * d;
            d = ((c + 64) == label ? 1.0f : 0.0f) - q4.x * invs; partial += d * d;
            d = ((c + 65) == label ? 1.0f : 0.0f) - q4.y * invs; partial += d * d;
            d = ((c + 66) == label ? 1.0f : 0.0f) - q4.z * invs; partial += d * d;
            d = ((c + 67) == label ? 1.0f : 0.0f) - q4.w * invs; partial += d * d;
            if (sub == 0) {
                float c0 = ar0 - bxs, c1 = ar1 - bys;
                float c2 = ar2 - f2,  c3 = ar3 - f3;
                partial += c0 * c0 + c1 * c1 + c2 * c2 + c3 * c3;   // coord
                float u = 1.0f - conf;
                partial += 5.0f * u * u;                            // obj
            }
        } else if (sub == 0) {
            partial += (objdet ? 0.0f : 1.0f) * conf * conf;        // noobj
        }
    }

    // block reduction -> one partial store
    float vsum = partial;
#pragma unroll
    for (int off = 32; off; off >>= 1) vsum += __shfl_xor(vsum, off);
    __shared__ float red[4];
    int wave = tid >> 6;
    if ((tid & 63) == 0) red[wave] = vsum;
    __syncthreads();
    if (tid == 0) partials[bid] = 0.5f * (red[0] + red[1] + red[2] + red[3]);
}

__global__ void reduce_kernel(const float* __restrict__ partials,
                              float* __restrict__ out)
{
    __shared__ float red[4];
    float s = 0.0f;
    for (int i = threadIdx.x; i < NBLK; i += 256) s += partials[i];
#pragma unroll
    for (int off = 32; off; off >>= 1) s += __shfl_xor(s, off);
    int wave = threadIdx.x >> 6;
    if ((threadIdx.x & 63) == 0) red[wave] = s;
    __syncthreads();
    if (threadIdx.x == 0) out[0] = red[0] + red[1] + red[2] + red[3];
}

extern "C" void kernel_launch(void* const* d_in, const int* in_sizes, int n_in,
                              void* d_out, int out_size, void* d_ws, size_t ws_size,
                              hipStream_t stream)
{
    const float* preds0  = (const float*)d_in[0];
    const float* preds1  = (const float*)d_in[1];
    const float* preds2  = (const float*)d_in[2];
    const float* gt      = (const float*)d_in[3];
    const float* anchors = (const float*)d_in[4];
    float* out = (float*)d_out;
    char* ws = (char*)d_ws;

    setup_kernel<<<BB, 64, 0, stream>>>(gt, anchors, ws);
    main_kernel<<<NBLK, 256, 0, stream>>>(preds0, preds1, preds2, anchors,
                                          (const char*)ws,
                                          (float*)(ws + WS_PART), out);
    reduce_kernel<<<1, 256, 0, stream>>>((const float*)(ws + WS_PART), out);
}